// Round 2
// baseline (1205.770 us; speedup 1.0000x reference)
//
#include <hip/hip_runtime.h>

// x:   (2,4,8,8,8,96,96) fp32   strides: b 18874368, ci 4718592, cd 589824, t 73728, d 9216, h 96, w 1
// W:   (9,4,4,3,3,3)     fp32   strides: ij 432, o 108, ci 27, kd 9, kh 3, kw 1
// b:   (9,4)             fp32
// out: (2,4,6,6,8,96,96) fp32   strides: b 10616832, o 2654208, c 442368, t 73728, d 9216, h 96, w 1

#define BLOCK 256

// launch_bounds(256,3): allow up to ~170 VGPRs (3 waves/EU) — we need ~150 for
// the 9x10 hoisted row buffer + 32 accumulators without spilling.
__global__ __launch_bounds__(256, 3) void conv5d_kernel(
    const float* __restrict__ xg,
    const float* __restrict__ Wg,
    const float* __restrict__ bg,
    float* __restrict__ outg)
{
    // Weights in LDS, transposed so the 4 'o' values are contiguous:
    // wl layout: [ci][ij][kd][kh][kw][o]  (broadcast ds_read_b128 per (kd,kh,kw))
    __shared__ float wl[3888];
    for (int k = threadIdx.x; k < 3888; k += BLOCK) {
        int o  = k & 3;  int r = k >> 2;
        int kw = r % 3;  r /= 3;
        int kh = r % 3;  r /= 3;
        int kd = r % 3;  r /= 3;
        int ij = r % 9;  int ci = r / 9;
        wl[k] = Wg[ij*432 + o*108 + ci*27 + kd*9 + kh*3 + kw];
    }
    __syncthreads();

    int gid = blockIdx.x * BLOCK + threadIdx.x;   // exact: 663552 threads, 2592 blocks
    int wv  = gid % 12;  int tmp = gid / 12;
    int h   = tmp % 96;  tmp /= 96;
    int d   = tmp % 8;   tmp /= 8;
    int t   = tmp % 6;   tmp /= 6;
    int c   = tmp % 6;   tmp /= 6;
    int b   = tmp;       // 0..1
    int w0  = wv * 8;

    const float* xb = xg + (size_t)b * 18874368;

    float acc[4][8];
    #pragma unroll
    for (int o = 0; o < 4; ++o)
        #pragma unroll
        for (int v = 0; v < 8; ++v) acc[o][v] = 0.f;

    // Edge-load offsets, computed once (branchless clamped addresses)
    const int eo0 = (w0 > 0)  ? -1 : 0;   // w-1 neighbor (clamped in-bounds)
    const int eo9 = (w0 < 88) ?  8 : 7;   // w+8 neighbor (clamped in-bounds)
    const bool we0 = (w0 > 0);
    const bool we9 = (w0 < 88);

    for (int ci = 0; ci < 4; ++ci) {
        for (int i = 0; i < 3; ++i) {
            for (int j = 0; j < 3; ++j) {
                const float* xp  = xb + (size_t)ci*4718592
                                      + (size_t)(c + i)*589824
                                      + (size_t)(t + j)*73728;
                const float* wlp = &wl[(ci*9 + i*3 + j) * 108];

                // ---- burst-load phase: all 9 (kd,kh) rows, 10 floats each ----
                float r[9][10];
                #pragma unroll
                for (int kd = 0; kd < 3; ++kd) {
                    int dd = d + kd - 1;
                    bool vd = (unsigned)dd < 8u;
                    #pragma unroll
                    for (int kh = 0; kh < 3; ++kh) {
                        int hh = h + kh - 1;
                        bool v = vd && ((unsigned)hh < 96u);
                        // invalid rows read a safe dummy row (xp itself), zeroed below
                        const float* xr = xp + (v ? (dd*9216 + hh*96) : 0) + w0;
                        float  e0 = xr[eo0];
                        float4 m0 = *(const float4*)(xr);
                        float4 m1 = *(const float4*)(xr + 4);
                        float  e9 = xr[eo9];
                        int q = kd*3 + kh;
                        r[q][0] = (v && we0) ? e0   : 0.f;
                        r[q][1] = v ? m0.x : 0.f;
                        r[q][2] = v ? m0.y : 0.f;
                        r[q][3] = v ? m0.z : 0.f;
                        r[q][4] = v ? m0.w : 0.f;
                        r[q][5] = v ? m1.x : 0.f;
                        r[q][6] = v ? m1.y : 0.f;
                        r[q][7] = v ? m1.z : 0.f;
                        r[q][8] = v ? m1.w : 0.f;
                        r[q][9] = (v && we9) ? e9   : 0.f;
                    }
                }

                // ---- compute phase: 9 rows x 3 kw x 8 w x 4 o = 864 FMAs ----
                #pragma unroll
                for (int q = 0; q < 9; ++q) {
                    const float* wrow = wlp + q*12;    // [kw][o], o contiguous
                    #pragma unroll
                    for (int kw = 0; kw < 3; ++kw) {
                        float4 w4 = *(const float4*)(wrow + kw*4);
                        #pragma unroll
                        for (int v = 0; v < 8; ++v) {
                            float xx = r[q][v + kw];
                            acc[0][v] = fmaf(xx, w4.x, acc[0][v]);
                            acc[1][v] = fmaf(xx, w4.y, acc[1][v]);
                            acc[2][v] = fmaf(xx, w4.z, acc[2][v]);
                            acc[3][v] = fmaf(xx, w4.w, acc[3][v]);
                        }
                    }
                }
            }
        }
    }

    // mean bias over the 9 (i,j) taps
    float mb[4];
    #pragma unroll
    for (int o = 0; o < 4; ++o) {
        float s = 0.f;
        #pragma unroll
        for (int ij = 0; ij < 9; ++ij) s += bg[ij*4 + o];
        mb[o] = s * (1.0f / 9.0f);
    }

    const float inv9 = 1.0f / 9.0f;
    size_t obase = (size_t)b*10616832 + (size_t)c*442368 + (size_t)t*73728
                 + (size_t)d*9216 + (size_t)h*96 + (size_t)w0;
    #pragma unroll
    for (int o = 0; o < 4; ++o) {
        float4 r0, r1;
        r0.x = acc[o][0]*inv9 + mb[o];
        r0.y = acc[o][1]*inv9 + mb[o];
        r0.z = acc[o][2]*inv9 + mb[o];
        r0.w = acc[o][3]*inv9 + mb[o];
        r1.x = acc[o][4]*inv9 + mb[o];
        r1.y = acc[o][5]*inv9 + mb[o];
        r1.z = acc[o][6]*inv9 + mb[o];
        r1.w = acc[o][7]*inv9 + mb[o];
        float* op = outg + obase + (size_t)o*2654208;
        *(float4*)(op)     = r0;
        *(float4*)(op + 4) = r1;
    }
}

extern "C" void kernel_launch(void* const* d_in, const int* in_sizes, int n_in,
                              void* d_out, int out_size, void* d_ws, size_t ws_size,
                              hipStream_t stream) {
    const float* x = (const float*)d_in[0];
    const float* W = (const float*)d_in[1];
    const float* b = (const float*)d_in[2];
    float* out = (float*)d_out;
    conv5d_kernel<<<2592, BLOCK, 0, stream>>>(x, W, b, out);
}